// Round 1
// baseline (542.997 us; speedup 1.0000x reference)
//
#include <hip/hip_runtime.h>

#define BB 1024
#define TT 512
#define KK 64

__global__ void crf_zero_loss(float* out) {
    out[(size_t)BB * TT] = 0.0f;
}

__global__ __launch_bounds__(128, 1)
void crf_fwd_kernel(const float* __restrict__ logits,
                    const int* __restrict__ nwords,
                    const int* __restrict__ tags,
                    const float* __restrict__ trans,
                    float* __restrict__ out) {
    __shared__ __align__(16) float sA[KK];          // viterbi alpha broadcast buffer
    __shared__ __align__(16) float sP[KK];          // lse p broadcast buffer
    __shared__ unsigned char sBP[TT * KK];          // backpointers, rows 1..len-1
    __shared__ unsigned char sTag[TT];              // backtraced tags staging

    const int b    = blockIdx.x;
    const int tid  = threadIdx.x;
    const int lane = tid & 63;
    const int wid  = tid >> 6;
    const int len  = nwords[b];
    const float* lg = logits + (size_t)b * TT * KK;

    if (wid == 0) {
        // ---------------- Viterbi wave ----------------
        float tc[KK];
#pragma unroll
        for (int i = 0; i < KK; ++i) tc[i] = trans[i * KK + lane];

        float alpha = lg[lane];          // t = 0
        sA[lane] = alpha;

        for (int t = 1; t < len; ++t) {
            float best = -__builtin_inff();
            int   bidx = 0;
#pragma unroll
            for (int q = 0; q < KK / 4; ++q) {
                const float4 a4 = reinterpret_cast<const float4*>(sA)[q];
                { float s = a4.x + tc[4*q+0]; if (s > best) { best = s; bidx = 4*q+0; } }
                { float s = a4.y + tc[4*q+1]; if (s > best) { best = s; bidx = 4*q+1; } }
                { float s = a4.z + tc[4*q+2]; if (s > best) { best = s; bidx = 4*q+2; } }
                { float s = a4.w + tc[4*q+3]; if (s > best) { best = s; bidx = 4*q+3; } }
            }
            const float logit = lg[t * KK + lane];
            alpha = best + logit;
            sBP[t * KK + lane] = (unsigned char)bidx;
            sA[lane] = alpha;            // same-wave LDS ops are in-order
        }

        // last = first-occurrence argmax over lanes of alpha
        float v = alpha;
        int   idx = lane;
#pragma unroll
        for (int m = 32; m >= 1; m >>= 1) {
            const float ov = __shfl_xor(v, m);
            const int   oi = __shfl_xor(idx, m);
            if (ov > v || (ov == v && oi < idx)) { v = ov; idx = oi; }
        }
        const int last = idx;            // wave-uniform

        // tail: positions len-1 .. T-1 are all `last`
        for (int t = len - 1 + lane; t < TT; t += 64)
            out[(size_t)b * TT + t] = (float)last;

        // backtrace through LDS backpointers (uniform broadcast byte reads)
        int tag = last;
        for (int t = len - 1; t >= 1; --t) {
            tag = sBP[t * KK + tag];
            sTag[t - 1] = (unsigned char)tag;   // all lanes write same value
        }
        // coalesced prediction writes for 0 .. len-2
        for (int t = lane; t < len - 1; t += 64)
            out[(size_t)b * TT + t] = (float)sTag[t];

    } else {
        // ---------------- logsumexp + score wave ----------------
        float E[KK];
#pragma unroll
        for (int i = 0; i < KK; ++i) E[i] = __expf(trans[i * KK + lane]);

        float a = lg[lane];              // t = 0 alpha (normalized repr)
        float C = 0.0f;                  // accumulated log-scale
        int   tprev = tags[b * TT];
        float acc = (lane == tprev) ? a : 0.0f;   // unary for t = 0

        for (int t = 1; t < len; ++t) {
            // wave max of a
            float M = a;
#pragma unroll
            for (int m = 32; m >= 1; m >>= 1) M = fmaxf(M, __shfl_xor(M, m));
            const float p = __expf(a - M);
            sP[lane] = p;

            float s0 = 0.f, s1 = 0.f, s2 = 0.f, s3 = 0.f;
#pragma unroll
            for (int q = 0; q < KK / 4; ++q) {
                const float4 p4 = reinterpret_cast<const float4*>(sP)[q];
                s0 = fmaf(p4.x, E[4*q+0], s0);
                s1 = fmaf(p4.y, E[4*q+1], s1);
                s2 = fmaf(p4.z, E[4*q+2], s2);
                s3 = fmaf(p4.w, E[4*q+3], s3);
            }
            const float sum   = (s0 + s1) + (s2 + s3);
            const float logit = lg[t * KK + lane];
            a = __logf(sum) + logit;
            C += M;

            const int tg = tags[b * TT + t];
            if (lane == tg) acc += logit;                    // unary
            if (lane == 0)  acc += trans[tprev * KK + tg];   // binary
            tprev = tg;
        }

        // log_norm = C + logsumexp over lanes of a
        float M = a;
#pragma unroll
        for (int m = 32; m >= 1; m >>= 1) M = fmaxf(M, __shfl_xor(M, m));
        float e = __expf(a - M);
#pragma unroll
        for (int m = 32; m >= 1; m >>= 1) e += __shfl_xor(e, m);
        const float log_norm = C + M + __logf(e);

        // score = lane-sum of acc
#pragma unroll
        for (int m = 32; m >= 1; m >>= 1) acc += __shfl_xor(acc, m);

        if (lane == 0)
            atomicAdd(out + (size_t)BB * TT, (log_norm - acc) * (1.0f / BB));
    }
}

extern "C" void kernel_launch(void* const* d_in, const int* in_sizes, int n_in,
                              void* d_out, int out_size, void* d_ws, size_t ws_size,
                              hipStream_t stream) {
    const float* logits = (const float*)d_in[0];
    const int*   nwords = (const int*)d_in[1];
    const int*   tags   = (const int*)d_in[2];
    const float* trans  = (const float*)d_in[3];
    float*       out    = (float*)d_out;

    crf_zero_loss<<<1, 1, 0, stream>>>(out);
    crf_fwd_kernel<<<BB, 128, 0, stream>>>(logits, nwords, tags, trans, out);
}